// Round 1
// baseline (1714.100 us; speedup 1.0000x reference)
//
#include <hip/hip_runtime.h>
#include <math.h>

#define WW 64
#define HH 64
#define L 4096     // WW*HH spatial positions
#define NC 64      // channels
#define D3 576     // NC*3*3

// ---------------- wave helpers ----------------
__device__ __forceinline__ float wave_max(float v){
  #pragma unroll
  for(int o=32;o;o>>=1) v = fmaxf(v, __shfl_xor(v,o));
  return v;
}
__device__ __forceinline__ float wave_sum(float v){
  #pragma unroll
  for(int o=32;o;o>>=1) v += __shfl_xor(v,o);
  return v;
}

// ---------------- builders ----------------
// p=1: Bhat[l,c] = (bg[c,l]+1e-7)/||.||  ; PfgBox[q,c] = 3x3 box-sum of fg (zero pad)
__global__ __launch_bounds__(64) void build_p1(const float* __restrict__ fg,
                                               const float* __restrict__ mask,
                                               float* __restrict__ Bhat,
                                               float* __restrict__ PfgBox){
  const int l = blockIdx.x, z = blockIdx.y, c = threadIdx.x;
  const float* fgz = fg + (size_t)z*NC*L;
  const float m = mask[(size_t)z*L + l];
  const float K = fgz[(size_t)c*L + l]*(1.0f-m) + 1e-7f;
  float ss = K*K;
  ss = wave_sum(ss);
  const float rn = rsqrtf(ss);
  Bhat[((size_t)z*L + l)*NC + c] = K*rn;

  const int y = l >> 6, x = l & 63;
  float s = 0.f;
  #pragma unroll
  for(int dy=-1;dy<=1;dy++){
    const int yy = y+dy;
    if(yy<0||yy>=HH) continue;
    #pragma unroll
    for(int dx=-1;dx<=1;dx++){
      const int xx = x+dx;
      if(xx<0||xx>=WW) continue;
      s += fgz[(size_t)c*L + yy*WW + xx];
    }
  }
  PfgBox[((size_t)z*L + l)*NC + c] = s;
}

// p=3: Bhat[l,(c,i,j)] = (bg_padded[c,y+i-1,x+j-1]+1e-7)/||.||  (OOB -> 1e-7, included in norm)
__global__ __launch_bounds__(64) void build_bhat3(const float* __restrict__ fg,
                                                  const float* __restrict__ mask,
                                                  float* __restrict__ Bhat){
  const int l = blockIdx.x, z = blockIdx.y, c = threadIdx.x;
  const float* fgz = fg + (size_t)z*NC*L;
  const float* mz  = mask + (size_t)z*L;
  const int y = l >> 6, x = l & 63;
  float K[9]; float ss = 0.f;
  #pragma unroll
  for(int i=0;i<3;i++){
    #pragma unroll
    for(int j=0;j<3;j++){
      const int yy = y+i-1, xx = x+j-1;
      float v = 0.f;
      if(yy>=0&&yy<HH&&xx>=0&&xx<WW){
        const int q = yy*WW+xx;
        v = fgz[(size_t)c*L + q]*(1.0f - mz[q]);
      }
      v += 1e-7f;
      K[i*3+j] = v; ss += v*v;
    }
  }
  ss = wave_sum(ss);
  const float rn = rsqrtf(ss);
  float* outp = Bhat + ((size_t)z*L + l)*D3 + c*9;
  #pragma unroll
  for(int k=0;k<9;k++) outp[k] = K[k]*rn;
}

// p=3: PfgBox[q=(y,x),(c,i,j)] = sum_{dy,dx in 3x3, center in-grid} fg_zpad[c, y+dy+i-1, x+dx+j-1]
__global__ __launch_bounds__(64) void build_pfgbox3(const float* __restrict__ fg,
                                                    float* __restrict__ PfgBox){
  const int l = blockIdx.x, z = blockIdx.y, c = threadIdx.x;
  const float* fgc = fg + ((size_t)z*NC + c)*L;
  const int y = l >> 6, x = l & 63;
  float acc[9] = {0.f,0.f,0.f,0.f,0.f,0.f,0.f,0.f,0.f};
  for(int dy=-1;dy<=1;dy++){
    const int yy = y+dy;
    if(yy<0||yy>=HH) continue;
    for(int dx=-1;dx<=1;dx++){
      const int xx = x+dx;
      if(xx<0||xx>=WW) continue;
      #pragma unroll
      for(int i=0;i<3;i++){
        const int py = yy+i-1;
        if(py<0||py>=HH) continue;
        #pragma unroll
        for(int j=0;j<3;j++){
          const int px = xx+j-1;
          if(px<0||px>=WW) continue;
          acc[i*3+j] += fgc[py*WW+px];
        }
      }
    }
  }
  float* outp = PfgBox + ((size_t)z*L + l)*D3 + c*9;
  #pragma unroll
  for(int k=0;k<9;k++) outp[k] = acc[k];
}

// ---------------- generic 64x64-tile fp32 GEMM ----------------
// BT=true : C[m,n] = sum_k A[m,k] * B[n,k]   (NT)
// BT=false: C[m,n] = sum_k A[m,k] * B[k,n]   (NN)
template<bool BT>
__global__ __launch_bounds__(256) void gemm64(const float* __restrict__ A, int lda, size_t sAz,
                                              const float* __restrict__ B, int ldb, size_t sBz,
                                              float* __restrict__ C, int ldc, size_t sCz,
                                              int Kdim){
  __shared__ float As[16][76];
  __shared__ float Bs[16][76];
  const int z = blockIdx.z;
  A += (size_t)z*sAz; B += (size_t)z*sBz; C += (size_t)z*sCz;
  const int bm = blockIdx.y*64, bn = blockIdx.x*64;
  const int t = threadIdx.x;
  const int tx = t & 15, ty = t >> 4;
  const int lr = t >> 2, lk = (t & 3) << 2;
  float acc[4][4] = {};

  for(int k0=0;k0<Kdim;k0+=16){
    {
      const float4 av = *(const float4*)(A + (size_t)(bm+lr)*lda + (k0+lk));
      As[lk+0][lr]=av.x; As[lk+1][lr]=av.y; As[lk+2][lr]=av.z; As[lk+3][lr]=av.w;
    }
    if (BT){
      const float4 bv = *(const float4*)(B + (size_t)(bn+lr)*ldb + (k0+lk));
      Bs[lk+0][lr]=bv.x; Bs[lk+1][lr]=bv.y; Bs[lk+2][lr]=bv.z; Bs[lk+3][lr]=bv.w;
    } else {
      const int kk = t >> 4, c4 = (t & 15) << 2;
      const float4 bv = *(const float4*)(B + (size_t)(k0+kk)*ldb + (bn+c4));
      *(float4*)&Bs[kk][c4] = bv;
    }
    __syncthreads();
    #pragma unroll
    for(int k=0;k<16;k++){
      float a[4], b[4];
      #pragma unroll
      for(int i=0;i<4;i++) a[i] = As[k][ty*4+i];
      #pragma unroll
      for(int j=0;j<4;j++) b[j] = Bs[k][tx*4+j];
      #pragma unroll
      for(int i=0;i<4;i++)
        #pragma unroll
        for(int j=0;j<4;j++) acc[i][j] = fmaf(a[i], b[j], acc[i][j]);
    }
    __syncthreads();
  }
  #pragma unroll
  for(int i=0;i<4;i++){
    float4 v; v.x=acc[i][0]; v.y=acc[i][1]; v.z=acc[i][2]; v.w=acc[i][3];
    *(float4*)(C + (size_t)(bm+ty*4+i)*ldc + bn + tx*4) = v;
  }
}

// ---------------- row softmax over 4096 ----------------
__global__ __launch_bounds__(256) void softmax4096(float* __restrict__ S, int rowsPerZ){
  __shared__ float red[4];
  float* p = S + ((size_t)blockIdx.y*rowsPerZ + blockIdx.x)*L;
  const int t = threadIdx.x;
  float4 v[4];
  float mx = -3.0e38f;
  #pragma unroll
  for(int i=0;i<4;i++){
    v[i] = ((const float4*)p)[i*256+t];
    mx = fmaxf(mx, fmaxf(fmaxf(v[i].x,v[i].y), fmaxf(v[i].z,v[i].w)));
  }
  mx = wave_max(mx);
  if((t&63)==0) red[t>>6]=mx;
  __syncthreads();
  mx = fmaxf(fmaxf(red[0],red[1]), fmaxf(red[2],red[3]));
  __syncthreads();
  float s = 0.f;
  #pragma unroll
  for(int i=0;i<4;i++){
    v[i].x=__expf(v[i].x-mx); v[i].y=__expf(v[i].y-mx);
    v[i].z=__expf(v[i].z-mx); v[i].w=__expf(v[i].w-mx);
    s += v[i].x+v[i].y+v[i].z+v[i].w;
  }
  s = wave_sum(s);
  if((t&63)==0) red[t>>6]=s;
  __syncthreads();
  s = red[0]+red[1]+red[2]+red[3];
  const float inv = 1.0f/s;
  #pragma unroll
  for(int i=0;i<4;i++){
    v[i].x*=inv; v[i].y*=inv; v[i].z*=inv; v[i].w*=inv;
    ((float4*)p)[i*256+t] = v[i];
  }
}

// ---------------- scatters (conv-transpose + mask mix) ----------------
__global__ __launch_bounds__(256) void scatter_p1(const float* __restrict__ R,
                                                  const float* __restrict__ fg,
                                                  const float* __restrict__ mask,
                                                  float* __restrict__ outs){
  const int z = blockIdx.y;
  const int idx = blockIdx.x*256 + threadIdx.x;  // [0, NC*L)
  const int c = idx >> 12, q = idx & 4095;
  const float m = mask[(size_t)z*L + q];
  const float rec = R[((size_t)z*L + q)*NC + c];
  const float f = fg[((size_t)z*NC + c)*L + q];
  outs[((size_t)z*128 + c)*L + q] = rec*m + f*(1.0f-m);
}

__global__ __launch_bounds__(256) void scatter_p3(const float* __restrict__ R,
                                                  const float* __restrict__ fg,
                                                  const float* __restrict__ mask,
                                                  float* __restrict__ outs){
  const int z = blockIdx.y;
  const int idx = blockIdx.x*256 + threadIdx.x;
  const int c = idx >> 12, q = idx & 4095;
  const int u = q >> 6, v = q & 63;
  float rec = 0.f;
  #pragma unroll
  for(int i=0;i<3;i++){
    const int yy = u+1-i;
    if(yy<0||yy>=HH) continue;
    #pragma unroll
    for(int j=0;j<3;j++){
      const int xx = v+1-j;
      if(xx<0||xx>=WW) continue;
      rec += R[((size_t)z*L + yy*WW+xx)*D3 + c*9 + i*3 + j];
    }
  }
  const float m = mask[(size_t)z*L + q];
  const float f = fg[((size_t)z*NC + c)*L + q];
  outs[((size_t)z*128 + 64 + c)*L + q] = rec*m*(1.0f/9.0f) + f*(1.0f-m);
}

// ---------------- SE module ----------------
__global__ __launch_bounds__(256) void se_reduce(const float* __restrict__ outs,
                                                 float* __restrict__ svec){
  __shared__ float red[4];
  const int ch = blockIdx.x, z = blockIdx.y;
  const float* p = outs + ((size_t)z*128 + ch)*L;
  const int t = threadIdx.x;
  float s = 0.f;
  #pragma unroll
  for(int i=0;i<4;i++){
    const float4 vv = ((const float4*)p)[i*256+t];
    s += vv.x+vv.y+vv.z+vv.w;
  }
  s = wave_sum(s);
  if((t&63)==0) red[t>>6]=s;
  __syncthreads();
  if(t==0) svec[z*128+ch] = (red[0]+red[1]+red[2]+red[3])*(1.0f/4096.0f);
}

__global__ __launch_bounds__(128) void se_mlp(const float* __restrict__ svec,
                                              const float* __restrict__ W1, const float* __restrict__ b1,
                                              const float* __restrict__ W2, const float* __restrict__ b2,
                                              float* __restrict__ g){
  __shared__ float s[128], h[128];
  const int z = blockIdx.x, i = threadIdx.x;
  s[i] = svec[z*128+i];
  __syncthreads();
  float a = b1[i];
  const float* w = W1 + (size_t)i*128;
  for(int j=0;j<128;j++) a = fmaf(w[j], s[j], a);
  h[i] = fmaxf(a, 0.f);
  __syncthreads();
  float o = b2[i];
  w = W2 + (size_t)i*128;
  for(int j=0;j<128;j++) o = fmaf(w[j], h[j], o);
  g[z*128+i] = 1.0f/(1.0f + __expf(-o));
}

// ---------------- combiner 1x1 conv ----------------
__global__ __launch_bounds__(256) void combiner(const float* __restrict__ outs,
                                                const float* __restrict__ g,
                                                const float* __restrict__ Wc,
                                                const float* __restrict__ bc,
                                                float* __restrict__ out){
  const size_t idx = (size_t)blockIdx.x*256 + threadIdx.x;
  const int q = (int)(idx & 4095);
  const int o = (int)((idx >> 12) & 63);
  const int z = (int)(idx >> 18);
  const float* ob = outs + (size_t)z*128*L + q;
  const float* gz = g + z*128;
  const float* wr = Wc + (size_t)o*128;
  float acc = bc[o];
  for(int ch=0; ch<128; ++ch) acc = fmaf(ob[(size_t)ch*L]*gz[ch], wr[ch], acc);
  out[idx] = acc;
}

// ---------------- host orchestration ----------------
extern "C" void kernel_launch(void* const* d_in, const int* in_sizes, int n_in,
                              void* d_out, int out_size, void* d_ws, size_t ws_size,
                              hipStream_t stream){
  const float* fg   = (const float*)d_in[0];
  const float* mask = (const float*)d_in[1];
  const float* W1   = (const float*)d_in[2];
  const float* b1   = (const float*)d_in[3];
  const float* W2   = (const float*)d_in[4];
  const float* b2   = (const float*)d_in[5];
  const float* Wc   = (const float*)d_in[6];
  const float* bc   = (const float*)d_in[7];
  float* out = (float*)d_out;

  char* w = (char*)d_ws;
  size_t off = 0;
  auto alloc = [&](size_t bytes)->float*{
    float* p = (float*)(w + off);
    off += (bytes + 255) & ~(size_t)255;
    return p;
  };
  float* Bhat   = alloc(2ull*L*D3*4);   // reused by p=1 (as 2 x L x 64) and p=3
  float* PfgBox = alloc(2ull*L*D3*4);
  float* Rbuf   = alloc(2ull*L*D3*4);
  float* outs   = alloc(2ull*128*L*4);
  float* svec   = alloc(2*128*4);
  float* gbuf   = alloc(2*128*4);
  const size_t fixed = off;

  int chunk = 4096;
  while (chunk > 256 && fixed + 2ull*chunk*L*4 > ws_size) chunk >>= 1;
  float* S = alloc(2ull*chunk*L*4);

  // ================= p=1 branch (channels 0..63 of outs) =================
  build_p1<<<dim3(L,2),64,0,stream>>>(fg, mask, Bhat, PfgBox);
  for(int q0=0;q0<L;q0+=chunk){
    gemm64<true ><<<dim3(L/64, chunk/64, 2),256,0,stream>>>(
        PfgBox + (size_t)q0*NC, NC, (size_t)L*NC,
        Bhat,                   NC, (size_t)L*NC,
        S,                      L,  (size_t)chunk*L, NC);
    softmax4096<<<dim3(chunk,2),256,0,stream>>>(S, chunk);
    gemm64<false><<<dim3(1, chunk/64, 2),256,0,stream>>>(
        S,                      L,  (size_t)chunk*L,
        Bhat,                   NC, (size_t)L*NC,
        Rbuf + (size_t)q0*NC,   NC, (size_t)L*NC, L);
  }
  scatter_p1<<<dim3(NC*L/256,2),256,0,stream>>>(Rbuf, fg, mask, outs);

  // ================= p=3 branch (channels 64..127 of outs) =================
  build_bhat3  <<<dim3(L,2),64,0,stream>>>(fg, mask, Bhat);
  build_pfgbox3<<<dim3(L,2),64,0,stream>>>(fg, PfgBox);
  for(int q0=0;q0<L;q0+=chunk){
    gemm64<true ><<<dim3(L/64, chunk/64, 2),256,0,stream>>>(
        PfgBox + (size_t)q0*D3, D3, (size_t)L*D3,
        Bhat,                   D3, (size_t)L*D3,
        S,                      L,  (size_t)chunk*L, D3);
    softmax4096<<<dim3(chunk,2),256,0,stream>>>(S, chunk);
    gemm64<false><<<dim3(D3/64, chunk/64, 2),256,0,stream>>>(
        S,                      L,  (size_t)chunk*L,
        Bhat,                   D3, (size_t)L*D3,
        Rbuf + (size_t)q0*D3,   D3, (size_t)L*D3, L);
  }
  scatter_p3<<<dim3(NC*L/256,2),256,0,stream>>>(Rbuf, fg, mask, outs);

  // ================= SE + combiner =================
  se_reduce<<<dim3(128,2),256,0,stream>>>(outs, svec);
  se_mlp<<<2,128,0,stream>>>(svec, W1, b1, W2, b2, gbuf);
  combiner<<<(2*64*L)/256,256,0,stream>>>(outs, gbuf, Wc, bc, out);
}

// Round 2
// 555.625 us; speedup vs baseline: 3.0850x; 3.0850x over previous
//
#include <hip/hip_runtime.h>
#include <math.h>

#define WW 64
#define HH 64
#define L 4096     // WW*HH spatial positions
#define NC 64      // channels
#define D3 576     // NC*3*3

typedef _Float16 f16x8 __attribute__((ext_vector_type(8)));
typedef _Float16 f16x4 __attribute__((ext_vector_type(4)));
typedef float    f32x4 __attribute__((ext_vector_type(4)));

// ---------------- wave helpers ----------------
__device__ __forceinline__ float wave_max(float v){
  #pragma unroll
  for(int o=32;o;o>>=1) v = fmaxf(v, __shfl_xor(v,o));
  return v;
}
__device__ __forceinline__ float wave_sum(float v){
  #pragma unroll
  for(int o=32;o;o>>=1) v += __shfl_xor(v,o);
  return v;
}

__device__ __forceinline__ void gload16(const void* g, void* l){
  __builtin_amdgcn_global_load_lds((const __attribute__((address_space(1))) unsigned int*)g,
                                   (__attribute__((address_space(3))) unsigned int*)l,
                                   16, 0, 0);
}

// ---------------- builders (fp16 outputs) ----------------
__global__ __launch_bounds__(64) void build_p1(const float* __restrict__ fg,
                                               const float* __restrict__ mask,
                                               _Float16* __restrict__ BhatH1,
                                               _Float16* __restrict__ PfgH1){
  const int l = blockIdx.x, z = blockIdx.y, c = threadIdx.x;
  const float* fgz = fg + (size_t)z*NC*L;
  const float m = mask[(size_t)z*L + l];
  const float K = fgz[(size_t)c*L + l]*(1.0f-m) + 1e-7f;
  float ss = K*K;
  ss = wave_sum(ss);
  const float rn = rsqrtf(ss);
  BhatH1[((size_t)z*L + l)*NC + c] = (_Float16)(K*rn);

  const int y = l >> 6, x = l & 63;
  float s = 0.f;
  #pragma unroll
  for(int dy=-1;dy<=1;dy++){
    const int yy = y+dy;
    if(yy<0||yy>=HH) continue;
    #pragma unroll
    for(int dx=-1;dx<=1;dx++){
      const int xx = x+dx;
      if(xx<0||xx>=WW) continue;
      s += fgz[(size_t)c*L + yy*WW + xx];
    }
  }
  PfgH1[((size_t)z*L + l)*NC + c] = (_Float16)s;
}

__global__ __launch_bounds__(64) void build_bhat3(const float* __restrict__ fg,
                                                  const float* __restrict__ mask,
                                                  _Float16* __restrict__ BhatH3){
  const int l = blockIdx.x, z = blockIdx.y, c = threadIdx.x;
  const float* fgz = fg + (size_t)z*NC*L;
  const float* mz  = mask + (size_t)z*L;
  const int y = l >> 6, x = l & 63;
  float K[9]; float ss = 0.f;
  #pragma unroll
  for(int i=0;i<3;i++){
    #pragma unroll
    for(int j=0;j<3;j++){
      const int yy = y+i-1, xx = x+j-1;
      float v = 0.f;
      if(yy>=0&&yy<HH&&xx>=0&&xx<WW){
        const int q = yy*WW+xx;
        v = fgz[(size_t)c*L + q]*(1.0f - mz[q]);
      }
      v += 1e-7f;
      K[i*3+j] = v; ss += v*v;
    }
  }
  ss = wave_sum(ss);
  const float rn = rsqrtf(ss);
  _Float16* outp = BhatH3 + ((size_t)z*L + l)*D3 + c*9;
  #pragma unroll
  for(int k=0;k<9;k++) outp[k] = (_Float16)(K[k]*rn);
}

__global__ __launch_bounds__(64) void build_pfgbox3(const float* __restrict__ fg,
                                                    _Float16* __restrict__ PfgH3){
  const int l = blockIdx.x, z = blockIdx.y, c = threadIdx.x;
  const float* fgc = fg + ((size_t)z*NC + c)*L;
  const int y = l >> 6, x = l & 63;
  float acc[9] = {0.f,0.f,0.f,0.f,0.f,0.f,0.f,0.f,0.f};
  for(int dy=-1;dy<=1;dy++){
    const int yy = y+dy;
    if(yy<0||yy>=HH) continue;
    for(int dx=-1;dx<=1;dx++){
      const int xx = x+dx;
      if(xx<0||xx>=WW) continue;
      #pragma unroll
      for(int i=0;i<3;i++){
        const int py = yy+i-1;
        if(py<0||py>=HH) continue;
        #pragma unroll
        for(int j=0;j<3;j++){
          const int px = xx+j-1;
          if(px<0||px>=WW) continue;
          acc[i*3+j] += fgc[py*WW+px];
        }
      }
    }
  }
  _Float16* outp = PfgH3 + ((size_t)z*L + l)*D3 + c*9;
  #pragma unroll
  for(int k=0;k<9;k++) outp[k] = (_Float16)acc[k];
}

// ---------------- zero fill (for padded transposed buffers) ----------------
__global__ __launch_bounds__(256) void zero_h(_Float16* __restrict__ p, size_t n){
  const size_t i = (size_t)blockIdx.x*256 + threadIdx.x;
  if(i < n) p[i] = (_Float16)0.f;
}

// ---------------- fp16 transpose: src (L x C) -> dst (C x L) ----------------
__global__ __launch_bounds__(256) void transpose_h(const ushort* __restrict__ src,
                                                   ushort* __restrict__ dst,
                                                   int C, size_t sSz, size_t sDz){
  __shared__ ushort tile[64][65];
  const int z = blockIdx.z;
  src += z*sSz; dst += z*sDz;
  const int bc = blockIdx.x*64, br = blockIdx.y*64;
  const int tx = threadIdx.x & 15, ty = threadIdx.x >> 4;
  #pragma unroll
  for(int i=0;i<4;i++){
    const ushort4 v = *(const ushort4*)(src + (size_t)(br+ty+16*i)*C + bc + tx*4);
    tile[ty+16*i][tx*4+0] = v.x;
    tile[ty+16*i][tx*4+1] = v.y;
    tile[ty+16*i][tx*4+2] = v.z;
    tile[ty+16*i][tx*4+3] = v.w;
  }
  __syncthreads();
  #pragma unroll
  for(int i=0;i<4;i++){
    ushort4 o;
    o.x = tile[tx*4+0][ty+16*i];
    o.y = tile[tx*4+1][ty+16*i];
    o.z = tile[tx*4+2][ty+16*i];
    o.w = tile[tx*4+3][ty+16*i];
    *(ushort4*)(dst + (size_t)(bc+ty+16*i)*L + br + tx*4) = o;
  }
}

// ---------------- fp16 NT MFMA GEMM: C[m,n] = sum_k A[m,k]*B[n,k] ----------------
// 128x128 tile, BK=64, 4 waves (2x2), each wave 64x64 via 4x4 frags of 16x16x32.
// LDS XOR-swizzle (byte ^= (row&7)<<4) applied via pre-swizzled global source
// for global_load_lds (linear dest) + swizzled ds_read (rule: both-sides).
__global__ __launch_bounds__(256) void gemm_h16(const _Float16* __restrict__ A, int lda, size_t sAz,
                                                const _Float16* __restrict__ B, int ldb, size_t sBz,
                                                float* __restrict__ C, int ldc, size_t sCz,
                                                int K){
  __shared__ _Float16 As[128*64];
  __shared__ _Float16 Bs[128*64];
  const int z = blockIdx.z;
  A += z*sAz; B += z*sBz; C += z*sCz;
  const int bm = blockIdx.y*128, bn = blockIdx.x*128;
  const int t = threadIdx.x, lane = t & 63, wave = t >> 6;
  const int wr = wave >> 1, wc = wave & 1;
  const int r16 = lane & 15, g4 = lane >> 4;
  const int srow = t >> 3;       // staging: row within 32-row group
  const int schunk = t & 7;      // staging: 16B chunk within 128B row
  f32x4 acc[4][4] = {};

  for(int k0=0;k0<K;k0+=64){
    #pragma unroll
    for(int u=0;u<4;u++){
      const int rowA = u*32 + srow;
      const int colh = ((schunk ^ (rowA & 7)) << 3);   // pre-swizzled source column (halves)
      gload16(A + (size_t)(bm+rowA)*lda + k0 + colh, (char*)As + u*4096 + wave*1024);
      gload16(B + (size_t)(bn+rowA)*ldb + k0 + colh, (char*)Bs + u*4096 + wave*1024);
    }
    __syncthreads();
    #pragma unroll
    for(int kk=0;kk<2;kk++){
      f16x8 af[4], bf[4];
      #pragma unroll
      for(int i=0;i<4;i++){
        const int row = wr*64 + i*16 + r16;
        const int off = ((row<<7) + kk*64 + (g4<<4)) ^ ((row&7)<<4);
        af[i] = *(const f16x8*)((const char*)As + off);
      }
      #pragma unroll
      for(int j=0;j<4;j++){
        const int row = wc*64 + j*16 + r16;
        const int off = ((row<<7) + kk*64 + (g4<<4)) ^ ((row&7)<<4);
        bf[j] = *(const f16x8*)((const char*)Bs + off);
      }
      #pragma unroll
      for(int i=0;i<4;i++)
        #pragma unroll
        for(int j=0;j<4;j++)
          acc[i][j] = __builtin_amdgcn_mfma_f32_16x16x32_f16(af[i], bf[j], acc[i][j], 0, 0, 0);
    }
    __syncthreads();
  }
  #pragma unroll
  for(int i=0;i<4;i++){
    const int row0 = bm + wr*64 + i*16 + g4*4;
    #pragma unroll
    for(int j=0;j<4;j++){
      const int col = bn + wc*64 + j*16 + r16;
      #pragma unroll
      for(int r=0;r<4;r++)
        C[(size_t)(row0+r)*ldc + col] = acc[i][j][r];
    }
  }
}

// ---------------- row softmax over 4096 (fp32 in, fp16 out) ----------------
__global__ __launch_bounds__(256) void softmax_h(const float* __restrict__ S,
                                                 _Float16* __restrict__ att,
                                                 int rowsPerZ){
  __shared__ float red[4];
  const size_t base = ((size_t)blockIdx.y*rowsPerZ + blockIdx.x)*L;
  const float* p = S + base;
  const int t = threadIdx.x;
  float4 v[4];
  float mx = -3.0e38f;
  #pragma unroll
  for(int i=0;i<4;i++){
    v[i] = ((const float4*)p)[i*256+t];
    mx = fmaxf(mx, fmaxf(fmaxf(v[i].x,v[i].y), fmaxf(v[i].z,v[i].w)));
  }
  mx = wave_max(mx);
  if((t&63)==0) red[t>>6]=mx;
  __syncthreads();
  mx = fmaxf(fmaxf(red[0],red[1]), fmaxf(red[2],red[3]));
  __syncthreads();
  float s = 0.f;
  #pragma unroll
  for(int i=0;i<4;i++){
    v[i].x=__expf(v[i].x-mx); v[i].y=__expf(v[i].y-mx);
    v[i].z=__expf(v[i].z-mx); v[i].w=__expf(v[i].w-mx);
    s += v[i].x+v[i].y+v[i].z+v[i].w;
  }
  s = wave_sum(s);
  if((t&63)==0) red[t>>6]=s;
  __syncthreads();
  s = red[0]+red[1]+red[2]+red[3];
  const float inv = 1.0f/s;
  _Float16* o = att + base;
  #pragma unroll
  for(int i=0;i<4;i++){
    f16x4 h;
    h[0] = (_Float16)(v[i].x*inv); h[1] = (_Float16)(v[i].y*inv);
    h[2] = (_Float16)(v[i].z*inv); h[3] = (_Float16)(v[i].w*inv);
    *(f16x4*)(o + i*1024 + t*4) = h;
  }
}

// ---------------- scatters (conv-transpose + mask mix) ----------------
__global__ __launch_bounds__(256) void scatter_p1(const float* __restrict__ R,
                                                  const float* __restrict__ fg,
                                                  const float* __restrict__ mask,
                                                  float* __restrict__ outs){
  const int z = blockIdx.y;
  const int idx = blockIdx.x*256 + threadIdx.x;
  const int c = idx >> 12, q = idx & 4095;
  const float m = mask[(size_t)z*L + q];
  const float rec = R[((size_t)z*L + q)*128 + c];
  const float f = fg[((size_t)z*NC + c)*L + q];
  outs[((size_t)z*128 + c)*L + q] = rec*m + f*(1.0f-m);
}

__global__ __launch_bounds__(256) void scatter_p3(const float* __restrict__ R,
                                                  const float* __restrict__ fg,
                                                  const float* __restrict__ mask,
                                                  float* __restrict__ outs){
  const int z = blockIdx.y;
  const int idx = blockIdx.x*256 + threadIdx.x;
  const int c = idx >> 12, q = idx & 4095;
  const int u = q >> 6, v = q & 63;
  float rec = 0.f;
  #pragma unroll
  for(int i=0;i<3;i++){
    const int yy = u+1-i;
    if(yy<0||yy>=HH) continue;
    #pragma unroll
    for(int j=0;j<3;j++){
      const int xx = v+1-j;
      if(xx<0||xx>=WW) continue;
      rec += R[((size_t)z*L + yy*WW+xx)*640 + c*9 + i*3 + j];
    }
  }
  const float m = mask[(size_t)z*L + q];
  const float f = fg[((size_t)z*NC + c)*L + q];
  outs[((size_t)z*128 + 64 + c)*L + q] = rec*m*(1.0f/9.0f) + f*(1.0f-m);
}

// ---------------- SE module ----------------
__global__ __launch_bounds__(256) void se_reduce(const float* __restrict__ outs,
                                                 float* __restrict__ svec){
  __shared__ float red[4];
  const int ch = blockIdx.x, z = blockIdx.y;
  const float* p = outs + ((size_t)z*128 + ch)*L;
  const int t = threadIdx.x;
  float s = 0.f;
  #pragma unroll
  for(int i=0;i<4;i++){
    const float4 vv = ((const float4*)p)[i*256+t];
    s += vv.x+vv.y+vv.z+vv.w;
  }
  s = wave_sum(s);
  if((t&63)==0) red[t>>6]=s;
  __syncthreads();
  if(t==0) svec[z*128+ch] = (red[0]+red[1]+red[2]+red[3])*(1.0f/4096.0f);
}

__global__ __launch_bounds__(128) void se_mlp(const float* __restrict__ svec,
                                              const float* __restrict__ W1, const float* __restrict__ b1,
                                              const float* __restrict__ W2, const float* __restrict__ b2,
                                              float* __restrict__ g){
  __shared__ float s[128], h[128];
  const int z = blockIdx.x, i = threadIdx.x;
  s[i] = svec[z*128+i];
  __syncthreads();
  float a = b1[i];
  const float* w = W1 + (size_t)i*128;
  for(int j=0;j<128;j++) a = fmaf(w[j], s[j], a);
  h[i] = fmaxf(a, 0.f);
  __syncthreads();
  float o = b2[i];
  w = W2 + (size_t)i*128;
  for(int j=0;j<128;j++) o = fmaf(w[j], h[j], o);
  g[z*128+i] = 1.0f/(1.0f + __expf(-o));
}

// ---------------- combiner 1x1 conv ----------------
__global__ __launch_bounds__(256) void combiner(const float* __restrict__ outs,
                                                const float* __restrict__ g,
                                                const float* __restrict__ Wc,
                                                const float* __restrict__ bc,
                                                float* __restrict__ out){
  const size_t idx = (size_t)blockIdx.x*256 + threadIdx.x;
  const int q = (int)(idx & 4095);
  const int o = (int)((idx >> 12) & 63);
  const int z = (int)(idx >> 18);
  const float* ob = outs + (size_t)z*128*L + q;
  const float* gz = g + z*128;
  const float* wr = Wc + (size_t)o*128;
  float acc = bc[o];
  for(int ch=0; ch<128; ++ch) acc = fmaf(ob[(size_t)ch*L]*gz[ch], wr[ch], acc);
  out[idx] = acc;
}

// ---------------- host orchestration ----------------
extern "C" void kernel_launch(void* const* d_in, const int* in_sizes, int n_in,
                              void* d_out, int out_size, void* d_ws, size_t ws_size,
                              hipStream_t stream){
  const float* fg   = (const float*)d_in[0];
  const float* mask = (const float*)d_in[1];
  const float* W1   = (const float*)d_in[2];
  const float* b1   = (const float*)d_in[3];
  const float* W2   = (const float*)d_in[4];
  const float* b2   = (const float*)d_in[5];
  const float* Wc   = (const float*)d_in[6];
  const float* bc   = (const float*)d_in[7];
  float* out = (float*)d_out;

  char* w = (char*)d_ws;
  size_t off = 0;
  auto alloc = [&](size_t bytes)->void*{
    void* p = (void*)(w + off);
    off += (bytes + 255) & ~(size_t)255;
    return p;
  };
  _Float16* BhatH3 = (_Float16*)alloc(2ull*L*D3*2);
  _Float16* BhatT3 = (_Float16*)alloc(2ull*640*L*2);   // padded N: 576->640
  _Float16* PfgH3  = (_Float16*)alloc(2ull*L*D3*2);
  _Float16* BhatH1 = (_Float16*)alloc(2ull*L*64*2);
  _Float16* BhatT1 = (_Float16*)alloc(2ull*128*L*2);   // padded N: 64->128
  _Float16* PfgH1  = (_Float16*)alloc(2ull*L*64*2);
  float* Rbuf3 = (float*)alloc(2ull*L*640*4);
  float* Rbuf1 = (float*)alloc(2ull*L*128*4);
  float* outs  = (float*)alloc(2ull*128*L*4);
  float* svec  = (float*)alloc(1024);
  float* gbuf  = (float*)alloc(1024);

  int chunk = 4096;
  while (chunk > 128 && off + (size_t)chunk*L*12ull + 512 > ws_size) chunk >>= 1;
  float*    S    = (float*)alloc(2ull*chunk*L*4);
  _Float16* attH = (_Float16*)alloc(2ull*chunk*L*2);

  // ================= p=1 branch (channels 0..63 of outs) =================
  build_p1<<<dim3(L,2),64,0,stream>>>(fg, mask, BhatH1, PfgH1);
  zero_h<<<(unsigned)((2ull*128*L+255)/256),256,0,stream>>>(BhatT1, 2ull*128*L);
  transpose_h<<<dim3(1,64,2),256,0,stream>>>((const ushort*)BhatH1, (ushort*)BhatT1,
                                             64, (size_t)L*64, (size_t)128*L);
  for(int q0=0;q0<L;q0+=chunk){
    gemm_h16<<<dim3(L/128, chunk/128, 2),256,0,stream>>>(
        PfgH1 + (size_t)q0*64, 64, (size_t)L*64,
        BhatH1,                64, (size_t)L*64,
        S,                     L,  (size_t)chunk*L, 64);
    softmax_h<<<dim3(chunk,2),256,0,stream>>>(S, attH, chunk);
    gemm_h16<<<dim3(1, chunk/128, 2),256,0,stream>>>(
        attH,                  L,  (size_t)chunk*L,
        BhatT1,                L,  (size_t)128*L,
        Rbuf1 + (size_t)q0*128, 128, (size_t)L*128, L);
  }
  scatter_p1<<<dim3(NC*L/256,2),256,0,stream>>>(Rbuf1, fg, mask, outs);

  // ================= p=3 branch (channels 64..127 of outs) =================
  build_bhat3  <<<dim3(L,2),64,0,stream>>>(fg, mask, BhatH3);
  zero_h<<<(unsigned)((2ull*640*L+255)/256),256,0,stream>>>(BhatT3, 2ull*640*L);
  transpose_h<<<dim3(9,64,2),256,0,stream>>>((const ushort*)BhatH3, (ushort*)BhatT3,
                                             D3, (size_t)L*D3, (size_t)640*L);
  build_pfgbox3<<<dim3(L,2),64,0,stream>>>(fg, PfgH3);
  for(int q0=0;q0<L;q0+=chunk){
    gemm_h16<<<dim3(L/128, chunk/128, 2),256,0,stream>>>(
        PfgH3 + (size_t)q0*D3, D3, (size_t)L*D3,
        BhatH3,                D3, (size_t)L*D3,
        S,                     L,  (size_t)chunk*L, D3);
    softmax_h<<<dim3(chunk,2),256,0,stream>>>(S, attH, chunk);
    gemm_h16<<<dim3(5, chunk/128, 2),256,0,stream>>>(
        attH,                  L,  (size_t)chunk*L,
        BhatT3,                L,  (size_t)640*L,
        Rbuf3 + (size_t)q0*640, 640, (size_t)L*640, L);
  }
  scatter_p3<<<dim3(NC*L/256,2),256,0,stream>>>(Rbuf3, fg, mask, outs);

  // ================= SE + combiner =================
  se_reduce<<<dim3(128,2),256,0,stream>>>(outs, svec);
  se_mlp<<<2,128,0,stream>>>(svec, W1, b1, W2, b2, gbuf);
  combiner<<<(2*64*L)/256,256,0,stream>>>(outs, gbuf, Wc, bc, out);
}

// Round 3
// 399.737 us; speedup vs baseline: 4.2881x; 1.3900x over previous
//
#include <hip/hip_runtime.h>
#include <math.h>

#define WW 64
#define HH 64
#define L 4096     // WW*HH spatial positions
#define NC 64      // channels
#define D3 576     // NC*3*3

typedef _Float16 f16x8 __attribute__((ext_vector_type(8)));
typedef _Float16 f16x4 __attribute__((ext_vector_type(4)));
typedef float    f32x4 __attribute__((ext_vector_type(4)));

// ---------------- wave helpers ----------------
__device__ __forceinline__ float wave_max(float v){
  #pragma unroll
  for(int o=32;o;o>>=1) v = fmaxf(v, __shfl_xor(v,o));
  return v;
}
__device__ __forceinline__ float wave_sum(float v){
  #pragma unroll
  for(int o=32;o;o>>=1) v += __shfl_xor(v,o);
  return v;
}

__device__ __forceinline__ void gload16(const void* g, void* l){
  __builtin_amdgcn_global_load_lds((const __attribute__((address_space(1))) unsigned int*)g,
                                   (__attribute__((address_space(3))) unsigned int*)l,
                                   16, 0, 0);
}

// ---------------- fg transpose: (z,c,q) -> (z,q,c) ----------------
__global__ __launch_bounds__(256) void transpose_fg(const float* __restrict__ fg,
                                                    float* __restrict__ fgT){
  __shared__ float tile[64][65];
  const int z = blockIdx.y;
  const int q0 = blockIdx.x*64;
  const int tx = threadIdx.x & 63, ty = threadIdx.x >> 6;
  #pragma unroll
  for(int i=0;i<16;i++){
    const int c = ty*16 + i;
    tile[c][tx] = fg[((size_t)z*64 + c)*L + q0 + tx];
  }
  __syncthreads();
  #pragma unroll
  for(int i=0;i<16;i++){
    const int q = ty*16 + i;
    fgT[((size_t)z*L + q0 + q)*64 + tx] = tile[tx][q];
  }
}

// ---------------- builders (fp16 outputs, coalesced via fgT) ----------------
__global__ __launch_bounds__(256) void build_p1(const float* __restrict__ fgT,
                                               const float* __restrict__ mask,
                                               _Float16* __restrict__ BhatH1,
                                               _Float16* __restrict__ PfgH1){
  const int t = threadIdx.x, c = t & 63, sub = t >> 6;
  const int l = blockIdx.x*4 + sub, z = blockIdx.y;
  const float* fgz = fgT + (size_t)z*L*64;
  const float m = mask[(size_t)z*L + l];
  const float K = fgz[(size_t)l*64 + c]*(1.0f-m) + 1e-7f;
  const float ss = wave_sum(K*K);
  BhatH1[((size_t)z*L + l)*NC + c] = (_Float16)(K*rsqrtf(ss));

  const int y = l >> 6, x = l & 63;
  float s = 0.f;
  #pragma unroll
  for(int dy=-1;dy<=1;dy++){
    const int yy = y+dy;
    if(yy<0||yy>=HH) continue;
    #pragma unroll
    for(int dx=-1;dx<=1;dx++){
      const int xx = x+dx;
      if(xx<0||xx>=WW) continue;
      s += fgz[(size_t)(yy*WW+xx)*64 + c];
    }
  }
  PfgH1[((size_t)z*L + l)*NC + c] = (_Float16)s;
}

__global__ __launch_bounds__(256) void build_bhat3(const float* __restrict__ fgT,
                                                   const float* __restrict__ mask,
                                                   _Float16* __restrict__ BhatH3){
  const int t = threadIdx.x, c = t & 63, sub = t >> 6;
  const int l = blockIdx.x*4 + sub, z = blockIdx.y;
  const float* fgz = fgT + (size_t)z*L*64;
  const float* mz  = mask + (size_t)z*L;
  const int y = l >> 6, x = l & 63;
  float K[9]; float ss = 0.f;
  #pragma unroll
  for(int i=0;i<3;i++){
    #pragma unroll
    for(int j=0;j<3;j++){
      const int yy = y+i-1, xx = x+j-1;
      float v = 0.f;
      if(yy>=0&&yy<HH&&xx>=0&&xx<WW){
        const int q = yy*WW+xx;
        v = fgz[(size_t)q*64 + c]*(1.0f - mz[q]);
      }
      v += 1e-7f;
      K[i*3+j] = v; ss += v*v;
    }
  }
  ss = wave_sum(ss);
  const float rn = rsqrtf(ss);
  _Float16* outp = BhatH3 + ((size_t)z*L + l)*D3 + c*9;
  #pragma unroll
  for(int k=0;k<9;k++) outp[k] = (_Float16)(K[k]*rn);
}

__global__ __launch_bounds__(256) void build_pfgbox3(const float* __restrict__ fgT,
                                                     _Float16* __restrict__ PfgH3){
  const int t = threadIdx.x, c = t & 63, sub = t >> 6;
  const int l = blockIdx.x*4 + sub, z = blockIdx.y;
  const float* fgz = fgT + (size_t)z*L*64;
  const int y = l >> 6, x = l & 63;
  // W[u][v] = fg[y+u-2, x+v-2] (zero OOB), u,v in 0..4
  float Wn[5][5];
  #pragma unroll
  for(int u=0;u<5;u++){
    const int yy = y+u-2;
    #pragma unroll
    for(int v=0;v<5;v++){
      const int xx = x+v-2;
      Wn[u][v] = (yy>=0 && yy<HH && xx>=0 && xx<WW) ? fgz[(size_t)(yy*WW+xx)*64 + c] : 0.f;
    }
  }
  const bool dyok[3] = { y-1>=0, true, y+1<HH };
  const bool dxok[3] = { x-1>=0, true, x+1<WW };
  _Float16* outp = PfgH3 + ((size_t)z*L + l)*D3 + c*9;
  #pragma unroll
  for(int i=0;i<3;i++){
    #pragma unroll
    for(int j=0;j<3;j++){
      float acc = 0.f;
      #pragma unroll
      for(int a=0;a<3;a++){
        if(!dyok[a]) continue;
        #pragma unroll
        for(int b=0;b<3;b++){
          if(!dxok[b]) continue;
          acc += Wn[i+a][j+b];
        }
      }
      outp[i*3+j] = (_Float16)acc;
    }
  }
}

// ---------------- zero fill (for padded transposed buffers) ----------------
__global__ __launch_bounds__(256) void zero_h(_Float16* __restrict__ p, size_t n){
  const size_t i = (size_t)blockIdx.x*256 + threadIdx.x;
  if(i < n) p[i] = (_Float16)0.f;
}

// ---------------- fp16 transpose: src (L x C) -> dst (C x L) ----------------
__global__ __launch_bounds__(256) void transpose_h(const ushort* __restrict__ src,
                                                   ushort* __restrict__ dst,
                                                   int C, size_t sSz, size_t sDz){
  __shared__ ushort tile[64][65];
  const int z = blockIdx.z;
  src += z*sSz; dst += z*sDz;
  const int bc = blockIdx.x*64, br = blockIdx.y*64;
  const int tx = threadIdx.x & 15, ty = threadIdx.x >> 4;
  #pragma unroll
  for(int i=0;i<4;i++){
    const ushort4 v = *(const ushort4*)(src + (size_t)(br+ty+16*i)*C + bc + tx*4);
    tile[ty+16*i][tx*4+0] = v.x;
    tile[ty+16*i][tx*4+1] = v.y;
    tile[ty+16*i][tx*4+2] = v.z;
    tile[ty+16*i][tx*4+3] = v.w;
  }
  __syncthreads();
  #pragma unroll
  for(int i=0;i<4;i++){
    ushort4 o;
    o.x = tile[tx*4+0][ty+16*i];
    o.y = tile[tx*4+1][ty+16*i];
    o.z = tile[tx*4+2][ty+16*i];
    o.w = tile[tx*4+3][ty+16*i];
    *(ushort4*)(dst + (size_t)(bc+ty+16*i)*L + br + tx*4) = o;
  }
}

// ---------------- fp16 NT MFMA GEMM: C[m,n] = sum_k A[m,k]*B[n,k] ----------------
__global__ __launch_bounds__(256) void gemm_h16(const _Float16* __restrict__ A, int lda, size_t sAz,
                                                const _Float16* __restrict__ B, int ldb, size_t sBz,
                                                float* __restrict__ C, int ldc, size_t sCz,
                                                int K){
  __shared__ _Float16 As[128*64];
  __shared__ _Float16 Bs[128*64];
  const int z = blockIdx.z;
  A += z*sAz; B += z*sBz; C += z*sCz;
  const int bm = blockIdx.y*128, bn = blockIdx.x*128;
  const int t = threadIdx.x, lane = t & 63, wave = t >> 6;
  const int wr = wave >> 1, wc = wave & 1;
  const int r16 = lane & 15, g4 = lane >> 4;
  const int srow = t >> 3;
  const int schunk = t & 7;
  f32x4 acc[4][4] = {};

  for(int k0=0;k0<K;k0+=64){
    #pragma unroll
    for(int u=0;u<4;u++){
      const int rowA = u*32 + srow;
      const int colh = ((schunk ^ (rowA & 7)) << 3);
      gload16(A + (size_t)(bm+rowA)*lda + k0 + colh, (char*)As + u*4096 + wave*1024);
      gload16(B + (size_t)(bn+rowA)*ldb + k0 + colh, (char*)Bs + u*4096 + wave*1024);
    }
    __syncthreads();
    #pragma unroll
    for(int kk=0;kk<2;kk++){
      f16x8 af[4], bf[4];
      #pragma unroll
      for(int i=0;i<4;i++){
        const int row = wr*64 + i*16 + r16;
        const int off = ((row<<7) + kk*64 + (g4<<4)) ^ ((row&7)<<4);
        af[i] = *(const f16x8*)((const char*)As + off);
      }
      #pragma unroll
      for(int j=0;j<4;j++){
        const int row = wc*64 + j*16 + r16;
        const int off = ((row<<7) + kk*64 + (g4<<4)) ^ ((row&7)<<4);
        bf[j] = *(const f16x8*)((const char*)Bs + off);
      }
      #pragma unroll
      for(int i=0;i<4;i++)
        #pragma unroll
        for(int j=0;j<4;j++)
          acc[i][j] = __builtin_amdgcn_mfma_f32_16x16x32_f16(af[i], bf[j], acc[i][j], 0, 0, 0);
    }
    __syncthreads();
  }
  #pragma unroll
  for(int i=0;i<4;i++){
    const int row0 = bm + wr*64 + i*16 + g4*4;
    #pragma unroll
    for(int j=0;j<4;j++){
      const int col = bn + wc*64 + j*16 + r16;
      #pragma unroll
      for(int r=0;r<4;r++)
        C[(size_t)(row0+r)*ldc + col] = acc[i][j][r];
    }
  }
}

// ---------------- row softmax over 4096 (fp32 in, fp16 out) ----------------
__global__ __launch_bounds__(256) void softmax_h(const float* __restrict__ S,
                                                 _Float16* __restrict__ att,
                                                 int rowsPerZ){
  __shared__ float red[4];
  const size_t base = ((size_t)blockIdx.y*rowsPerZ + blockIdx.x)*L;
  const float* p = S + base;
  const int t = threadIdx.x;
  float4 v[4];
  float mx = -3.0e38f;
  #pragma unroll
  for(int i=0;i<4;i++){
    v[i] = ((const float4*)p)[i*256+t];
    mx = fmaxf(mx, fmaxf(fmaxf(v[i].x,v[i].y), fmaxf(v[i].z,v[i].w)));
  }
  mx = wave_max(mx);
  if((t&63)==0) red[t>>6]=mx;
  __syncthreads();
  mx = fmaxf(fmaxf(red[0],red[1]), fmaxf(red[2],red[3]));
  __syncthreads();
  float s = 0.f;
  #pragma unroll
  for(int i=0;i<4;i++){
    v[i].x=__expf(v[i].x-mx); v[i].y=__expf(v[i].y-mx);
    v[i].z=__expf(v[i].z-mx); v[i].w=__expf(v[i].w-mx);
    s += v[i].x+v[i].y+v[i].z+v[i].w;
  }
  s = wave_sum(s);
  if((t&63)==0) red[t>>6]=s;
  __syncthreads();
  s = red[0]+red[1]+red[2]+red[3];
  const float inv = 1.0f/s;
  _Float16* o = att + base;
  #pragma unroll
  for(int i=0;i<4;i++){
    f16x4 h;
    h[0] = (_Float16)(v[i].x*inv); h[1] = (_Float16)(v[i].y*inv);
    h[2] = (_Float16)(v[i].z*inv); h[3] = (_Float16)(v[i].w*inv);
    *(f16x4*)(o + i*1024 + t*4) = h;
  }
}

// ---------------- scatters (conv-transpose + mask mix) ----------------
__global__ __launch_bounds__(256) void scatter_p1(const float* __restrict__ R,
                                                  const float* __restrict__ fg,
                                                  const float* __restrict__ mask,
                                                  float* __restrict__ outs){
  const int z = blockIdx.y;
  const int idx = blockIdx.x*256 + threadIdx.x;
  const int c = idx >> 12, q = idx & 4095;
  const float m = mask[(size_t)z*L + q];
  const float rec = R[((size_t)z*L + q)*128 + c];
  const float f = fg[((size_t)z*NC + c)*L + q];
  outs[((size_t)z*128 + c)*L + q] = rec*m + f*(1.0f-m);
}

__global__ __launch_bounds__(256) void scatter_p3(const float* __restrict__ R,
                                                  const float* __restrict__ fg,
                                                  const float* __restrict__ mask,
                                                  float* __restrict__ outs){
  const int z = blockIdx.y;
  const int idx = blockIdx.x*256 + threadIdx.x;
  const int c = idx >> 12, q = idx & 4095;
  const int u = q >> 6, v = q & 63;
  float rec = 0.f;
  #pragma unroll
  for(int i=0;i<3;i++){
    const int yy = u+1-i;
    if(yy<0||yy>=HH) continue;
    #pragma unroll
    for(int j=0;j<3;j++){
      const int xx = v+1-j;
      if(xx<0||xx>=WW) continue;
      rec += R[((size_t)z*L + yy*WW+xx)*640 + c*9 + i*3 + j];
    }
  }
  const float m = mask[(size_t)z*L + q];
  const float f = fg[((size_t)z*NC + c)*L + q];
  outs[((size_t)z*128 + 64 + c)*L + q] = rec*m*(1.0f/9.0f) + f*(1.0f-m);
}

// ---------------- SE module ----------------
__global__ __launch_bounds__(256) void se_reduce(const float* __restrict__ outs,
                                                 float* __restrict__ svec){
  __shared__ float red[4];
  const int ch = blockIdx.x, z = blockIdx.y;
  const float* p = outs + ((size_t)z*128 + ch)*L;
  const int t = threadIdx.x;
  float s = 0.f;
  #pragma unroll
  for(int i=0;i<4;i++){
    const float4 vv = ((const float4*)p)[i*256+t];
    s += vv.x+vv.y+vv.z+vv.w;
  }
  s = wave_sum(s);
  if((t&63)==0) red[t>>6]=s;
  __syncthreads();
  if(t==0) svec[z*128+ch] = (red[0]+red[1]+red[2]+red[3])*(1.0f/4096.0f);
}

__global__ __launch_bounds__(128) void se_mlp(const float* __restrict__ svec,
                                              const float* __restrict__ W1, const float* __restrict__ b1,
                                              const float* __restrict__ W2, const float* __restrict__ b2,
                                              float* __restrict__ g){
  __shared__ float s[128], h[128];
  const int z = blockIdx.x, i = threadIdx.x;
  s[i] = svec[z*128+i];
  __syncthreads();
  float a = b1[i];
  const float* w = W1 + (size_t)i*128;
  for(int j=0;j<128;j++) a = fmaf(w[j], s[j], a);
  h[i] = fmaxf(a, 0.f);
  __syncthreads();
  float o = b2[i];
  w = W2 + (size_t)i*128;
  for(int j=0;j<128;j++) o = fmaf(w[j], h[j], o);
  g[z*128+i] = 1.0f/(1.0f + __expf(-o));
}

// ---------------- combiner 1x1 conv ----------------
__global__ __launch_bounds__(256) void combiner(const float* __restrict__ outs,
                                                const float* __restrict__ g,
                                                const float* __restrict__ Wc,
                                                const float* __restrict__ bc,
                                                float* __restrict__ out){
  const size_t idx = (size_t)blockIdx.x*256 + threadIdx.x;
  const int q = (int)(idx & 4095);
  const int o = (int)((idx >> 12) & 63);
  const int z = (int)(idx >> 18);
  const float* ob = outs + (size_t)z*128*L + q;
  const float* gz = g + z*128;
  const float* wr = Wc + (size_t)o*128;
  float acc = bc[o];
  for(int ch=0; ch<128; ++ch) acc = fmaf(ob[(size_t)ch*L]*gz[ch], wr[ch], acc);
  out[idx] = acc;
}

// ---------------- host orchestration ----------------
extern "C" void kernel_launch(void* const* d_in, const int* in_sizes, int n_in,
                              void* d_out, int out_size, void* d_ws, size_t ws_size,
                              hipStream_t stream){
  const float* fg   = (const float*)d_in[0];
  const float* mask = (const float*)d_in[1];
  const float* W1   = (const float*)d_in[2];
  const float* b1   = (const float*)d_in[3];
  const float* W2   = (const float*)d_in[4];
  const float* b2   = (const float*)d_in[5];
  const float* Wc   = (const float*)d_in[6];
  const float* bc   = (const float*)d_in[7];
  float* out = (float*)d_out;

  char* w = (char*)d_ws;
  size_t off = 0;
  auto alloc = [&](size_t bytes)->void*{
    void* p = (void*)(w + off);
    off += (bytes + 255) & ~(size_t)255;
    return p;
  };
  _Float16* BhatH3 = (_Float16*)alloc(2ull*L*D3*2);
  _Float16* BhatT3 = (_Float16*)alloc(2ull*640*L*2);   // padded N: 576->640
  _Float16* PfgH3  = (_Float16*)alloc(2ull*L*D3*2);
  _Float16* BhatH1 = (_Float16*)alloc(2ull*L*64*2);
  _Float16* BhatT1 = (_Float16*)alloc(2ull*128*L*2);   // padded N: 64->128
  _Float16* PfgH1  = (_Float16*)alloc(2ull*L*64*2);
  float* fgT   = (float*)alloc(2ull*L*64*4);
  float* Rbuf3 = (float*)alloc(2ull*L*640*4);
  float* Rbuf1 = (float*)alloc(2ull*L*128*4);
  float* outs  = (float*)alloc(2ull*128*L*4);
  float* svec  = (float*)alloc(1024);
  float* gbuf  = (float*)alloc(1024);

  int chunk = 4096;
  while (chunk > 128 && off + (size_t)chunk*L*12ull + 512 > ws_size) chunk >>= 1;
  float*    S    = (float*)alloc(2ull*chunk*L*4);
  _Float16* attH = (_Float16*)alloc(2ull*chunk*L*2);

  transpose_fg<<<dim3(64,2),256,0,stream>>>(fg, fgT);

  // ================= p=1 branch (channels 0..63 of outs) =================
  build_p1<<<dim3(L/4,2),256,0,stream>>>(fgT, mask, BhatH1, PfgH1);
  zero_h<<<(unsigned)((2ull*128*L+255)/256),256,0,stream>>>(BhatT1, 2ull*128*L);
  transpose_h<<<dim3(1,64,2),256,0,stream>>>((const ushort*)BhatH1, (ushort*)BhatT1,
                                             64, (size_t)L*64, (size_t)128*L);
  for(int q0=0;q0<L;q0+=chunk){
    gemm_h16<<<dim3(L/128, chunk/128, 2),256,0,stream>>>(
        PfgH1 + (size_t)q0*64, 64, (size_t)L*64,
        BhatH1,                64, (size_t)L*64,
        S,                     L,  (size_t)chunk*L, 64);
    softmax_h<<<dim3(chunk,2),256,0,stream>>>(S, attH, chunk);
    gemm_h16<<<dim3(1, chunk/128, 2),256,0,stream>>>(
        attH,                  L,  (size_t)chunk*L,
        BhatT1,                L,  (size_t)128*L,
        Rbuf1 + (size_t)q0*128, 128, (size_t)L*128, L);
  }
  scatter_p1<<<dim3(NC*L/256,2),256,0,stream>>>(Rbuf1, fg, mask, outs);

  // ================= p=3 branch (channels 64..127 of outs) =================
  build_bhat3  <<<dim3(L/4,2),256,0,stream>>>(fgT, mask, BhatH3);
  zero_h<<<(unsigned)((2ull*640*L+255)/256),256,0,stream>>>(BhatT3, 2ull*640*L);
  transpose_h<<<dim3(9,64,2),256,0,stream>>>((const ushort*)BhatH3, (ushort*)BhatT3,
                                             D3, (size_t)L*D3, (size_t)640*L);
  build_pfgbox3<<<dim3(L/4,2),256,0,stream>>>(fgT, PfgH3);
  for(int q0=0;q0<L;q0+=chunk){
    gemm_h16<<<dim3(L/128, chunk/128, 2),256,0,stream>>>(
        PfgH3 + (size_t)q0*D3, D3, (size_t)L*D3,
        BhatH3,                D3, (size_t)L*D3,
        S,                     L,  (size_t)chunk*L, D3);
    softmax_h<<<dim3(chunk,2),256,0,stream>>>(S, attH, chunk);
    gemm_h16<<<dim3(5, chunk/128, 2),256,0,stream>>>(
        attH,                  L,  (size_t)chunk*L,
        BhatT3,                L,  (size_t)640*L,
        Rbuf3 + (size_t)q0*640, 640, (size_t)L*640, L);
  }
  scatter_p3<<<dim3(NC*L/256,2),256,0,stream>>>(Rbuf3, fg, mask, outs);

  // ================= SE + combiner =================
  se_reduce<<<dim3(128,2),256,0,stream>>>(outs, svec);
  se_mlp<<<2,128,0,stream>>>(svec, W1, b1, W2, b2, gbuf);
  combiner<<<(2*64*L)/256,256,0,stream>>>(outs, gbuf, Wc, bc, out);
}